// Round 4
// baseline (407.627 us; speedup 1.0000x reference)
//
#include <hip/hip_runtime.h>
#include <hip/hip_bf16.h>
#include <stdint.h>

#define NPIX 4096

typedef __attribute__((ext_vector_type(8))) short bf16x8;
typedef __attribute__((ext_vector_type(16))) float f32x16;
typedef __attribute__((ext_vector_type(4))) unsigned int uint4v;

__device__ __forceinline__ unsigned short bfb(float f) {
  __hip_bfloat16 h = __float2bfloat16(f);
  return __builtin_bit_cast(unsigned short, h);
}
__device__ __forceinline__ unsigned pack2(float a, float b) {
  return (unsigned)bfb(a) | ((unsigned)bfb(b) << 16);
}
__device__ __forceinline__ f32x16 mfma32(bf16x8 a, bf16x8 b, f32x16 c) {
  return __builtin_amdgcn_mfma_f32_32x32x16_bf16(a, b, c, 0, 0, 0);
}

// ---------------- kernel 0: convert weights to bf16 ----------------
__global__ void k_cvt(const float* __restrict__ Wq, const float* __restrict__ Wk,
                      const float* __restrict__ Wv, const float* __restrict__ Wr,
                      unsigned short* __restrict__ wqk, unsigned short* __restrict__ wv,
                      unsigned short* __restrict__ wr) {
  int i = blockIdx.x * 256 + threadIdx.x;  // 0..65535
  wqk[i] = bfb(i < 32768 ? Wq[i] : Wk[i - 32768]);
  wv[i]  = bfb(Wv[i]);
  wr[i]  = bfb(Wr[i]);
}

// ---------------- kernel 1: qkv projections ----------------
// out: qT [B][N][128] bf16, kT [B][N][128] bf16, v [B][256][N] bf16
__launch_bounds__(256, 2)
__global__ void k_qkv(const float* __restrict__ x,
                      const unsigned short* __restrict__ wqk,
                      const unsigned short* __restrict__ wv,
                      const float* __restrict__ bq, const float* __restrict__ bk,
                      const float* __restrict__ bv,
                      unsigned short* __restrict__ qT, unsigned short* __restrict__ kT,
                      unsigned short* __restrict__ vV) {
  __shared__ __align__(16) unsigned short xT[64 * 256];  // [n][c] bf16, swizzled rows of 512B
  const int b = blockIdx.x & 7;
  const int n0 = (blockIdx.x >> 3) * 64;
  const int t = threadIdx.x;
  const float* xb = x + (size_t)b * 256 * NPIX;
  #pragma unroll
  for (int p = 0; p < 16; ++p) {
    int c = (t >> 4) + p * 16;
    int nq = (t & 15) * 4;
    float4 f = *reinterpret_cast<const float4*>(xb + (size_t)c * NPIX + n0 + nq);
    float vals[4] = {f.x, f.y, f.z, f.w};
    #pragma unroll
    for (int j = 0; j < 4; ++j) {
      int n = nq + j;
      int byteoff = n * 512 + ((c * 2) ^ ((n & 7) << 4));
      xT[byteoff >> 1] = bfb(vals[j]);
    }
  }
  __syncthreads();
  const int lane = t & 63, w = t >> 6, l31 = lane & 31, hi = lane >> 5;
  f32x16 aq[2][2], av[2][2];
  #pragma unroll
  for (int a0 = 0; a0 < 2; ++a0)
    #pragma unroll
    for (int a1 = 0; a1 < 2; ++a1)
      #pragma unroll
      for (int i = 0; i < 16; ++i) { aq[a0][a1][i] = 0.f; av[a0][a1][i] = 0.f; }
  #pragma unroll
  for (int s = 0; s < 16; ++s) {  // K = 256 = 16 steps of 16
    bf16x8 xa[2];
    #pragma unroll
    for (int nt = 0; nt < 2; ++nt) {
      int n = nt * 32 + l31;
      int byteoff = n * 512 + (((s * 32 + hi * 16)) ^ ((n & 7) << 4));
      xa[nt] = *reinterpret_cast<const bf16x8*>(reinterpret_cast<const char*>(xT) + byteoff);
    }
    #pragma unroll
    for (int oc2 = 0; oc2 < 2; ++oc2) {
      int oc = w * 64 + oc2 * 32 + l31;
      bf16x8 wq = *reinterpret_cast<const bf16x8*>(wqk + oc * 256 + s * 16 + hi * 8);
      bf16x8 wvf = *reinterpret_cast<const bf16x8*>(wv + oc * 256 + s * 16 + hi * 8);
      #pragma unroll
      for (int nt = 0; nt < 2; ++nt) {
        aq[oc2][nt] = mfma32(xa[nt], wq, aq[oc2][nt]);   // D[n, oc]
        av[oc2][nt] = mfma32(wvf, xa[nt], av[oc2][nt]);  // D[vc, n]
      }
    }
  }
  #pragma unroll
  for (int oc2 = 0; oc2 < 2; ++oc2) {
    int oc = w * 64 + oc2 * 32 + l31;
    float bias = (oc < 128) ? bq[oc] : bk[oc - 128];
    unsigned short* dst = (oc < 128) ? (qT + (size_t)b * NPIX * 128 + oc)
                                     : (kT + (size_t)b * NPIX * 128 + (oc - 128));
    #pragma unroll
    for (int nt = 0; nt < 2; ++nt)
      #pragma unroll
      for (int r = 0; r < 16; ++r) {
        int n = n0 + nt * 32 + (r & 3) + 8 * (r >> 2) + 4 * hi;
        dst[(size_t)n * 128] = bfb(aq[oc2][nt][r] + bias);
      }
  }
  unsigned short* vb = vV + (size_t)b * 256 * NPIX;
  #pragma unroll
  for (int vc2 = 0; vc2 < 2; ++vc2)
    #pragma unroll
    for (int nt = 0; nt < 2; ++nt)
      #pragma unroll
      for (int r = 0; r < 16; ++r) {
        int vc = w * 64 + vc2 * 32 + (r & 3) + 8 * (r >> 2) + 4 * hi;
        int n = n0 + nt * 32 + l31;
        vb[(size_t)vc * NPIX + n] = bfb(av[vc2][nt][r] + bv[vc]);
      }
}

// ---------------- kernel 2: fused flash attention ----------------
// Grid 512 = 8 b x 64 q-tiles of 64. Block: 4 waves = (q-half) x (vc-half).
// Each wave: 32 q x 128 vc. QK^T duplicated across vc-halves (same S), softmax
// redundant but bit-identical -> no merge. S^T = K^T Q, O^T = V P^T.
__launch_bounds__(256, 3)
__global__ void k_attn(const unsigned short* __restrict__ qT,
                       const unsigned short* __restrict__ kT,
                       const unsigned short* __restrict__ vV,
                       unsigned short* __restrict__ oT) {
  __shared__ __align__(16) char smem[49152];  // K 16KB + V 32KB
  const int b = blockIdx.x & 7;          // XCD-affine: one batch per XCD
  const int qt = blockIdx.x >> 3;        // 0..63
  const int t = threadIdx.x, lane = t & 63, l31 = lane & 31, hi = lane >> 5;
  const int sw = t >> 6, qh = sw & 1, vh = sw >> 1;
  char* Kl = smem;
  char* Vl = smem + 16384;
  const int qp = qt * 64 + qh * 32 + l31;
  const unsigned short* qTb = qT + (size_t)b * NPIX * 128;
  const unsigned short* kTb = kT + (size_t)b * NPIX * 128;
  const unsigned short* vb  = vV + (size_t)b * 256 * NPIX;
  bf16x8 qf[8];
  #pragma unroll
  for (int s = 0; s < 8; ++s)
    qf[s] = *reinterpret_cast<const bf16x8*>(qTb + (size_t)qp * 128 + s * 16 + hi * 8);
  f32x16 O[4];
  #pragma unroll
  for (int vt = 0; vt < 4; ++vt)
    #pragma unroll
    for (int i = 0; i < 16; ++i) O[vt][i] = 0.f;
  float m_run = -3.0e38f, l_run = 0.0f;

  for (int kt = 0; kt < 64; ++kt) {
    const int kp0 = kt * 64;
    // stage K tile [64][128] bf16 (swizzled dest)
    #pragma unroll
    for (int i = 0; i < 4; ++i) {
      int row = sw * 16 + i * 4 + (lane >> 4);
      int c2 = (lane & 15) * 16;
      uint4v d = *reinterpret_cast<const uint4v*>(
          reinterpret_cast<const char*>(kTb) + (size_t)(kp0 + row) * 256 + c2);
      *reinterpret_cast<uint4v*>(Kl + row * 256 + (c2 ^ ((row & 7) << 4))) = d;
    }
    // stage V tile [256][64] bf16
    #pragma unroll
    for (int i = 0; i < 8; ++i) {
      int vc = sw * 64 + i * 8 + (lane >> 3);
      int c2 = (lane & 7) * 16;
      uint4v d = *reinterpret_cast<const uint4v*>(
          reinterpret_cast<const char*>(vb) + (size_t)vc * 8192 + kp0 * 2 + c2);
      *reinterpret_cast<uint4v*>(Vl + vc * 128 + (c2 ^ ((vc & 7) << 4))) = d;
    }
    __syncthreads();
    #pragma unroll
    for (int rt = 0; rt < 2; ++rt) {
      f32x16 S;
      #pragma unroll
      for (int i = 0; i < 16; ++i) S[i] = 0.f;
      __builtin_amdgcn_s_setprio(1);
      #pragma unroll
      for (int s = 0; s < 8; ++s) {  // d = 128 = 8 steps
        int row = rt * 32 + l31;
        int byteoff = row * 256 + ((s * 32 + hi * 16) ^ ((row & 7) << 4));
        bf16x8 ka = *reinterpret_cast<const bf16x8*>(Kl + byteoff);
        S = mfma32(ka, qf[s], S);  // S^T[kp][qp]
      }
      __builtin_amdgcn_s_setprio(0);
      // key-wise max: in-lane 16 + partner lane^32
      float mx = fmaxf(fmaxf(fmaxf(S[0], S[1]), fmaxf(S[2], S[3])),
                       fmaxf(fmaxf(S[4], S[5]), fmaxf(S[6], S[7])));
      mx = fmaxf(mx, fmaxf(fmaxf(fmaxf(S[8], S[9]), fmaxf(S[10], S[11])),
                           fmaxf(fmaxf(S[12], S[13]), fmaxf(S[14], S[15]))));
      mx = fmaxf(mx, __shfl_xor(mx, 32));
      if (__any(mx > m_run + 8.0f)) {  // defer-max (T13)
        float mn = fmaxf(m_run, mx);
        float al = __expf(m_run - mn);
        l_run *= al;
        #pragma unroll
        for (int vt = 0; vt < 4; ++vt)
          #pragma unroll
          for (int i = 0; i < 16; ++i) O[vt][i] *= al;
        m_run = mn;
      }
      float sum = 0.f;
      #pragma unroll
      for (int i = 0; i < 16; ++i) { S[i] = __expf(S[i] - m_run); sum += S[i]; }
      sum += __shfl_xor(sum, 32);
      l_run += sum;
      // pack P to bf16 fragments: pairs + half swaps
      unsigned wd[8];
      #pragma unroll
      for (int i = 0; i < 8; ++i) wd[i] = pack2(S[2 * i], S[2 * i + 1]);
      #pragma unroll
      for (int pr = 0; pr < 4; ++pr) {
        int ia = (pr & 1) + (pr >> 1) * 4;      // 0,1,4,5
        int ib = ia + 2;                         // 2,3,6,7
        unsigned xs = (unsigned)__shfl_xor((int)wd[ia], 32);
        unsigned ys = (unsigned)__shfl_xor((int)wd[ib], 32);
        unsigned na = hi ? ys : wd[ia];
        unsigned nb = hi ? wd[ib] : xs;
        wd[ia] = na; wd[ib] = nb;
      }
      bf16x8 pf[2];
      { uint4v u; u.x = wd[0]; u.y = wd[1]; u.z = wd[2]; u.w = wd[3];
        pf[0] = __builtin_bit_cast(bf16x8, u); }
      { uint4v u; u.x = wd[4]; u.y = wd[5]; u.z = wd[6]; u.w = wd[7];
        pf[1] = __builtin_bit_cast(bf16x8, u); }
      // PV: O^T[vc][qp] += V[vc,kp] * P^T[kp,qp]  (this wave's 128-vc half)
      __builtin_amdgcn_s_setprio(1);
      #pragma unroll
      for (int sl = 0; sl < 2; ++sl) {
        #pragma unroll
        for (int vt = 0; vt < 4; ++vt) {
          int vc = vh * 128 + vt * 32 + l31;
          int byteoff = vc * 128 + (((rt * 2 + sl) * 32 + hi * 16) ^ ((vc & 7) << 4));
          bf16x8 va = *reinterpret_cast<const bf16x8*>(Vl + byteoff);
          O[vt] = mfma32(va, pf[sl], O[vt]);
        }
      }
      __builtin_amdgcn_s_setprio(0);
    }
    __syncthreads();
  }
  float rl = 1.0f / l_run;
  unsigned short* oTb = oT + (size_t)b * NPIX * 256;  // [qp][vc]
  #pragma unroll
  for (int vt = 0; vt < 4; ++vt)
    #pragma unroll
    for (int i = 0; i < 16; i += 2) {
      int vc = vh * 128 + vt * 32 + (i & 3) + 8 * (i >> 2) + 4 * hi;
      unsigned pk = pack2(O[vt][i] * rl, O[vt][i + 1] * rl);
      *reinterpret_cast<unsigned*>(oTb + (size_t)qp * 256 + vc) = pk;
    }
}

// ---------------- kernel 3: output projection + residual ----------------
__launch_bounds__(256, 2)
__global__ void k_out(const unsigned short* __restrict__ oT,
                      const unsigned short* __restrict__ wr,
                      const float* __restrict__ br, const float* __restrict__ gamma,
                      const float* __restrict__ x, float* __restrict__ out) {
  const int b = blockIdx.x & 7;
  const int n0 = (blockIdx.x >> 3) * 64;
  const int t = threadIdx.x, w = t >> 6, lane = t & 63, l31 = lane & 31, hi = lane >> 5;
  const unsigned short* oTb = oT + (size_t)b * NPIX * 256;
  f32x16 acc[2][2];
  #pragma unroll
  for (int a0 = 0; a0 < 2; ++a0)
    #pragma unroll
    for (int a1 = 0; a1 < 2; ++a1)
      #pragma unroll
      for (int i = 0; i < 16; ++i) acc[a0][a1][i] = 0.f;
  #pragma unroll
  for (int s = 0; s < 16; ++s) {  // K = 256 (vc)
    bf16x8 ofr[2], wfr[2];
    #pragma unroll
    for (int nt = 0; nt < 2; ++nt) {
      int n = n0 + nt * 32 + l31;
      ofr[nt] = *reinterpret_cast<const bf16x8*>(oTb + (size_t)n * 256 + s * 16 + hi * 8);
    }
    #pragma unroll
    for (int c2 = 0; c2 < 2; ++c2) {
      int c = w * 64 + c2 * 32 + l31;
      wfr[c2] = *reinterpret_cast<const bf16x8*>(wr + c * 256 + s * 16 + hi * 8);
    }
    #pragma unroll
    for (int c2 = 0; c2 < 2; ++c2)
      #pragma unroll
      for (int nt = 0; nt < 2; ++nt)
        acc[c2][nt] = mfma32(wfr[c2], ofr[nt], acc[c2][nt]);  // D[c, n]
  }
  float g = gamma[0];
  #pragma unroll
  for (int c2 = 0; c2 < 2; ++c2)
    #pragma unroll
    for (int nt = 0; nt < 2; ++nt)
      #pragma unroll
      for (int r = 0; r < 16; ++r) {
        int c = w * 64 + c2 * 32 + (r & 3) + 8 * (r >> 2) + 4 * hi;
        int n = n0 + nt * 32 + l31;
        size_t idx = (size_t)b * 256 * NPIX + (size_t)c * NPIX + n;
        out[idx] = g * (acc[c2][nt][r] + br[c]) + x[idx];
      }
}

extern "C" void kernel_launch(void* const* d_in, const int* in_sizes, int n_in,
                              void* d_out, int out_size, void* d_ws, size_t ws_size,
                              hipStream_t stream) {
  const float* x     = (const float*)d_in[0];
  const float* Wk    = (const float*)d_in[1];
  const float* bk    = (const float*)d_in[2];
  const float* Wq    = (const float*)d_in[3];
  const float* bq    = (const float*)d_in[4];
  const float* Wv    = (const float*)d_in[5];
  const float* bv    = (const float*)d_in[6];
  const float* Wr    = (const float*)d_in[7];
  const float* br    = (const float*)d_in[8];
  const float* gamma = (const float*)d_in[9];

  const size_t OFF_QT  = 0;
  const size_t OFF_KT  = 8388608;
  const size_t OFF_V   = 16777216;
  const size_t OFF_OT  = 33554432;
  const size_t OFF_WQK = 50331648;
  const size_t OFF_WV  = 50462720;
  const size_t OFF_WR  = 50593792;
  const size_t NEED    = 50724864;
  if (ws_size < NEED) return;  // cannot run without scratch

  char* ws = (char*)d_ws;
  unsigned short* qT  = (unsigned short*)(ws + OFF_QT);
  unsigned short* kT  = (unsigned short*)(ws + OFF_KT);
  unsigned short* vV  = (unsigned short*)(ws + OFF_V);
  unsigned short* oT  = (unsigned short*)(ws + OFF_OT);
  unsigned short* wqk = (unsigned short*)(ws + OFF_WQK);
  unsigned short* wvb = (unsigned short*)(ws + OFF_WV);
  unsigned short* wrb = (unsigned short*)(ws + OFF_WR);

  k_cvt<<<256, 256, 0, stream>>>(Wq, Wk, Wv, Wr, wqk, wvb, wrb);
  k_qkv<<<512, 256, 0, stream>>>(x, wqk, wvb, bq, bk, bv, qT, kT, vV);
  k_attn<<<512, 256, 0, stream>>>(qT, kT, vV, oT);
  k_out<<<512, 256, 0, stream>>>(oT, wrb, br, gamma, x, (float*)d_out);
}

// Round 7
// 264.309 us; speedup vs baseline: 1.5422x; 1.5422x over previous
//
#include <hip/hip_runtime.h>
#include <hip/hip_bf16.h>
#include <stdint.h>

#define NPIX 4096

typedef __attribute__((ext_vector_type(8))) short bf16x8;
typedef __attribute__((ext_vector_type(16))) float f32x16;
typedef __attribute__((ext_vector_type(4))) unsigned int uint4v;

__device__ __forceinline__ unsigned short bfb(float f) {
  __hip_bfloat16 h = __float2bfloat16(f);
  return __builtin_bit_cast(unsigned short, h);
}
__device__ __forceinline__ unsigned pack2(float a, float b) {
  return (unsigned)bfb(a) | ((unsigned)bfb(b) << 16);
}
__device__ __forceinline__ f32x16 mfma32(bf16x8 a, bf16x8 b, f32x16 c) {
  return __builtin_amdgcn_mfma_f32_32x32x16_bf16(a, b, c, 0, 0, 0);
}

// ---------------- kernel 0: convert weights to bf16 ----------------
__global__ void k_cvt(const float* __restrict__ Wq, const float* __restrict__ Wk,
                      const float* __restrict__ Wv, const float* __restrict__ Wr,
                      unsigned short* __restrict__ wqk, unsigned short* __restrict__ wv,
                      unsigned short* __restrict__ wr) {
  int i = blockIdx.x * 256 + threadIdx.x;  // 0..65535
  wqk[i] = bfb(i < 32768 ? Wq[i] : Wk[i - 32768]);
  wv[i]  = bfb(Wv[i]);
  wr[i]  = bfb(Wr[i]);
}

// ---------------- kernel 1: qkv projections ----------------
// out: qT [B][N][128] bf16, kT [B][N][128] bf16, v [B][256][N] bf16
__launch_bounds__(256, 2)
__global__ void k_qkv(const float* __restrict__ x,
                      const unsigned short* __restrict__ wqk,
                      const unsigned short* __restrict__ wv,
                      const float* __restrict__ bq, const float* __restrict__ bk,
                      const float* __restrict__ bv,
                      unsigned short* __restrict__ qT, unsigned short* __restrict__ kT,
                      unsigned short* __restrict__ vV) {
  __shared__ __align__(16) unsigned short xT[64 * 256];  // [n][c] bf16, swizzled rows of 512B
  const int b = blockIdx.x & 7;
  const int n0 = (blockIdx.x >> 3) * 64;
  const int t = threadIdx.x;
  const float* xb = x + (size_t)b * 256 * NPIX;
  #pragma unroll
  for (int p = 0; p < 16; ++p) {
    int c = (t >> 4) + p * 16;
    int nq = (t & 15) * 4;
    float4 f = *reinterpret_cast<const float4*>(xb + (size_t)c * NPIX + n0 + nq);
    float vals[4] = {f.x, f.y, f.z, f.w};
    #pragma unroll
    for (int j = 0; j < 4; ++j) {
      int n = nq + j;
      int byteoff = n * 512 + ((c * 2) ^ ((n & 7) << 4));
      xT[byteoff >> 1] = bfb(vals[j]);
    }
  }
  __syncthreads();
  const int lane = t & 63, w = t >> 6, l31 = lane & 31, hi = lane >> 5;
  f32x16 aq[2][2], av[2][2];
  #pragma unroll
  for (int a0 = 0; a0 < 2; ++a0)
    #pragma unroll
    for (int a1 = 0; a1 < 2; ++a1)
      #pragma unroll
      for (int i = 0; i < 16; ++i) { aq[a0][a1][i] = 0.f; av[a0][a1][i] = 0.f; }
  #pragma unroll
  for (int s = 0; s < 16; ++s) {  // K = 256 = 16 steps of 16
    bf16x8 xa[2];
    #pragma unroll
    for (int nt = 0; nt < 2; ++nt) {
      int n = nt * 32 + l31;
      int byteoff = n * 512 + (((s * 32 + hi * 16)) ^ ((n & 7) << 4));
      xa[nt] = *reinterpret_cast<const bf16x8*>(reinterpret_cast<const char*>(xT) + byteoff);
    }
    #pragma unroll
    for (int oc2 = 0; oc2 < 2; ++oc2) {
      int oc = w * 64 + oc2 * 32 + l31;
      bf16x8 wq = *reinterpret_cast<const bf16x8*>(wqk + oc * 256 + s * 16 + hi * 8);
      bf16x8 wvf = *reinterpret_cast<const bf16x8*>(wv + oc * 256 + s * 16 + hi * 8);
      #pragma unroll
      for (int nt = 0; nt < 2; ++nt) {
        aq[oc2][nt] = mfma32(xa[nt], wq, aq[oc2][nt]);   // D[n, oc]
        av[oc2][nt] = mfma32(wvf, xa[nt], av[oc2][nt]);  // D[vc, n]
      }
    }
  }
  #pragma unroll
  for (int oc2 = 0; oc2 < 2; ++oc2) {
    int oc = w * 64 + oc2 * 32 + l31;
    float bias = (oc < 128) ? bq[oc] : bk[oc - 128];
    unsigned short* dst = (oc < 128) ? (qT + (size_t)b * NPIX * 128 + oc)
                                     : (kT + (size_t)b * NPIX * 128 + (oc - 128));
    #pragma unroll
    for (int nt = 0; nt < 2; ++nt)
      #pragma unroll
      for (int r = 0; r < 16; ++r) {
        int n = n0 + nt * 32 + (r & 3) + 8 * (r >> 2) + 4 * hi;
        dst[(size_t)n * 128] = bfb(aq[oc2][nt][r] + bias);
      }
  }
  unsigned short* vb = vV + (size_t)b * 256 * NPIX;
  #pragma unroll
  for (int vc2 = 0; vc2 < 2; ++vc2)
    #pragma unroll
    for (int nt = 0; nt < 2; ++nt)
      #pragma unroll
      for (int r = 0; r < 16; ++r) {
        int vc = w * 64 + vc2 * 32 + (r & 3) + 8 * (r >> 2) + 4 * hi;
        int n = n0 + nt * 32 + l31;
        vb[(size_t)vc * NPIX + n] = bfb(av[vc2][nt][r] + bv[vc]);
      }
}

// ---------------- kernel 2: fused flash attention (R1 structure + dbuf + T14) ----------------
// 4 waves x 32q x 256vc, QBLK=128, KVBLK=64. Double-buffered K/V staging with
// async issue-early/write-late split. K rows 256B swz ^((row&15)<<4); V packed
// 2 vc per 256B row, swz ^(((vc>>1)&15)<<4).
__launch_bounds__(256, 1)
__global__ void k_attn(const unsigned short* __restrict__ qT,
                       const unsigned short* __restrict__ kT,
                       const unsigned short* __restrict__ vV,
                       unsigned short* __restrict__ oT) {
  __shared__ __align__(16) char smem[98304];  // 2 x (K 16KB + V 32KB)
  const int b = blockIdx.x & 7;          // XCD-affine: one batch per XCD
  const int qt = blockIdx.x >> 3;
  const int t = threadIdx.x, lane = t & 63, l31 = lane & 31, hi = lane >> 5;
  const int sw = t >> 6;
  const int qp = qt * 128 + sw * 32 + l31;
  const unsigned short* qTb = qT + (size_t)b * NPIX * 128;
  const char* kTb = (const char*)(kT + (size_t)b * NPIX * 128);
  const char* vb  = (const char*)(vV + (size_t)b * 256 * NPIX);

  // per-thread staging geometry (constant across tiles)
  int kGl[4], kLds[4];
  #pragma unroll
  for (int i = 0; i < 4; ++i) {
    int row = sw * 16 + i * 4 + (lane >> 4);
    int c2 = (lane & 15) * 16;
    kGl[i]  = row * 256 + c2;                              // + kt*16384
    kLds[i] = row * 256 + (c2 ^ ((row & 15) << 4));
  }
  int vGl[8], vLds[8];
  #pragma unroll
  for (int i = 0; i < 8; ++i) {
    int vc = sw * 64 + i * 8 + (lane >> 3);
    int c2 = (lane & 7) * 16;
    vGl[i]  = vc * 8192 + c2;                              // + kt*128
    vLds[i] = (vc >> 1) * 256 + (((vc & 1) * 128 + c2) ^ (((vc >> 1) & 15) << 4));
  }
  // compute-phase read geometry
  int kRowBase[2], kRowSwz[2];
  #pragma unroll
  for (int rt = 0; rt < 2; ++rt) {
    int row = rt * 32 + l31;
    kRowBase[rt] = row * 256;
    kRowSwz[rt]  = (row & 15) << 4;
  }
  int vBase[8], vSwz[8], vHalf;
  #pragma unroll
  for (int vt = 0; vt < 8; ++vt) {
    int vc = vt * 32 + l31;
    vBase[vt] = (vc >> 1) * 256;
    vSwz[vt]  = ((vc >> 1) & 15) << 4;
  }
  vHalf = (l31 & 1) * 128;

  bf16x8 qf[8];
  #pragma unroll
  for (int s = 0; s < 8; ++s)
    qf[s] = *reinterpret_cast<const bf16x8*>(qTb + (size_t)qp * 128 + s * 16 + hi * 8);
  f32x16 O[8];
  #pragma unroll
  for (int vt = 0; vt < 8; ++vt)
    #pragma unroll
    for (int i = 0; i < 16; ++i) O[vt][i] = 0.f;
  float m_run = -3.0e38f, l_run = 0.0f;

  uint4v stK[4], stV[8];
  // prologue: load + write tile 0
  #pragma unroll
  for (int i = 0; i < 4; ++i) stK[i] = *reinterpret_cast<const uint4v*>(kTb + kGl[i]);
  #pragma unroll
  for (int i = 0; i < 8; ++i) stV[i] = *reinterpret_cast<const uint4v*>(vb + vGl[i]);
  #pragma unroll
  for (int i = 0; i < 4; ++i) *reinterpret_cast<uint4v*>(smem + kLds[i]) = stK[i];
  #pragma unroll
  for (int i = 0; i < 8; ++i) *reinterpret_cast<uint4v*>(smem + 16384 + vLds[i]) = stV[i];
  __syncthreads();

  for (int kt = 0; kt < 64; ++kt) {
    const int cur = kt & 1;
    char* Kl = smem + cur * 49152;
    char* Vl = smem + cur * 49152 + 16384;
    // issue next tile's global loads early (fly under compute)
    if (kt < 63) {
      const char* kg = kTb + (size_t)(kt + 1) * 16384;
      const char* vg = vb + (size_t)(kt + 1) * 128;
      #pragma unroll
      for (int i = 0; i < 4; ++i) stK[i] = *reinterpret_cast<const uint4v*>(kg + kGl[i]);
      #pragma unroll
      for (int i = 0; i < 8; ++i) stV[i] = *reinterpret_cast<const uint4v*>(vg + vGl[i]);
      __builtin_amdgcn_sched_barrier(0);  // pin load issue before compute
    }
    #pragma unroll
    for (int rt = 0; rt < 2; ++rt) {
      f32x16 S;
      #pragma unroll
      for (int i = 0; i < 16; ++i) S[i] = 0.f;
      __builtin_amdgcn_s_setprio(1);
      #pragma unroll
      for (int s = 0; s < 8; ++s) {  // d = 128 = 8 steps
        bf16x8 ka = *reinterpret_cast<const bf16x8*>(
            Kl + kRowBase[rt] + ((s * 32 + hi * 16) ^ kRowSwz[rt]));
        S = mfma32(ka, qf[s], S);  // S^T[kp][qp]
      }
      __builtin_amdgcn_s_setprio(0);
      // key-wise max: in-lane 16 + partner lane^32
      float mx = fmaxf(fmaxf(fmaxf(S[0], S[1]), fmaxf(S[2], S[3])),
                       fmaxf(fmaxf(S[4], S[5]), fmaxf(S[6], S[7])));
      mx = fmaxf(mx, fmaxf(fmaxf(fmaxf(S[8], S[9]), fmaxf(S[10], S[11])),
                           fmaxf(fmaxf(S[12], S[13]), fmaxf(S[14], S[15]))));
      mx = fmaxf(mx, __shfl_xor(mx, 32));
      if (__any(mx > m_run + 8.0f)) {  // defer-max (T13)
        float mn = fmaxf(m_run, mx);
        float al = __expf(m_run - mn);
        l_run *= al;
        #pragma unroll
        for (int vt = 0; vt < 8; ++vt)
          #pragma unroll
          for (int i = 0; i < 16; ++i) O[vt][i] *= al;
        m_run = mn;
      }
      float sum = 0.f;
      #pragma unroll
      for (int i = 0; i < 16; ++i) { S[i] = __expf(S[i] - m_run); sum += S[i]; }
      sum += __shfl_xor(sum, 32);
      l_run += sum;
      // pack P to bf16 fragments: pairs + half swaps
      unsigned wd[8];
      #pragma unroll
      for (int i = 0; i < 8; ++i) wd[i] = pack2(S[2 * i], S[2 * i + 1]);
      #pragma unroll
      for (int pr = 0; pr < 4; ++pr) {
        int ia = (pr & 1) + (pr >> 1) * 4;      // 0,1,4,5
        int ib = ia + 2;                         // 2,3,6,7
        unsigned xs = (unsigned)__shfl_xor((int)wd[ia], 32);
        unsigned ys = (unsigned)__shfl_xor((int)wd[ib], 32);
        unsigned na = hi ? ys : wd[ia];
        unsigned nb = hi ? wd[ib] : xs;
        wd[ia] = na; wd[ib] = nb;
      }
      bf16x8 pf[2];
      { uint4v u; u.x = wd[0]; u.y = wd[1]; u.z = wd[2]; u.w = wd[3];
        pf[0] = __builtin_bit_cast(bf16x8, u); }
      { uint4v u; u.x = wd[4]; u.y = wd[5]; u.z = wd[6]; u.w = wd[7];
        pf[1] = __builtin_bit_cast(bf16x8, u); }
      // PV: O^T[vc][qp] += V[vc,kp] * P^T[kp,qp]
      __builtin_amdgcn_s_setprio(1);
      #pragma unroll
      for (int sl = 0; sl < 2; ++sl) {
        int ks = rt * 2 + sl;
        #pragma unroll
        for (int vt = 0; vt < 8; ++vt) {
          bf16x8 va = *reinterpret_cast<const bf16x8*>(
              Vl + vBase[vt] + ((vHalf + ks * 32 + hi * 16) ^ vSwz[vt]));
          O[vt] = mfma32(va, pf[sl], O[vt]);
        }
      }
      __builtin_amdgcn_s_setprio(0);
    }
    __syncthreads();   // all waves done reading buf[cur] (and buf[cur^1] from kt-1)
    if (kt < 63) {
      char* Kn = smem + (cur ^ 1) * 49152;
      char* Vn = smem + (cur ^ 1) * 49152 + 16384;
      #pragma unroll
      for (int i = 0; i < 4; ++i) *reinterpret_cast<uint4v*>(Kn + kLds[i]) = stK[i];
      #pragma unroll
      for (int i = 0; i < 8; ++i) *reinterpret_cast<uint4v*>(Vn + vLds[i]) = stV[i];
    }
    __syncthreads();
  }
  float rl = 1.0f / l_run;
  unsigned short* oTb = oT + (size_t)b * NPIX * 256;  // [qp][vc]
  #pragma unroll
  for (int vt = 0; vt < 8; ++vt)
    #pragma unroll
    for (int i = 0; i < 16; i += 2) {
      int vc = vt * 32 + (i & 3) + 8 * (i >> 2) + 4 * hi;
      unsigned pk = pack2(O[vt][i] * rl, O[vt][i + 1] * rl);
      *reinterpret_cast<unsigned*>(oTb + (size_t)qp * 256 + vc) = pk;
    }
}

// ---------------- kernel 3: output projection + residual ----------------
__launch_bounds__(256, 2)
__global__ void k_out(const unsigned short* __restrict__ oT,
                      const unsigned short* __restrict__ wr,
                      const float* __restrict__ br, const float* __restrict__ gamma,
                      const float* __restrict__ x, float* __restrict__ out) {
  const int b = blockIdx.x & 7;
  const int n0 = (blockIdx.x >> 3) * 64;
  const int t = threadIdx.x, w = t >> 6, lane = t & 63, l31 = lane & 31, hi = lane >> 5;
  const unsigned short* oTb = oT + (size_t)b * NPIX * 256;
  f32x16 acc[2][2];
  #pragma unroll
  for (int a0 = 0; a0 < 2; ++a0)
    #pragma unroll
    for (int a1 = 0; a1 < 2; ++a1)
      #pragma unroll
      for (int i = 0; i < 16; ++i) acc[a0][a1][i] = 0.f;
  #pragma unroll
  for (int s = 0; s < 16; ++s) {  // K = 256 (vc)
    bf16x8 ofr[2], wfr[2];
    #pragma unroll
    for (int nt = 0; nt < 2; ++nt) {
      int n = n0 + nt * 32 + l31;
      ofr[nt] = *reinterpret_cast<const bf16x8*>(oTb + (size_t)n * 256 + s * 16 + hi * 8);
    }
    #pragma unroll
    for (int c2 = 0; c2 < 2; ++c2) {
      int c = w * 64 + c2 * 32 + l31;
      wfr[c2] = *reinterpret_cast<const bf16x8*>(wr + c * 256 + s * 16 + hi * 8);
    }
    #pragma unroll
    for (int c2 = 0; c2 < 2; ++c2)
      #pragma unroll
      for (int nt = 0; nt < 2; ++nt)
        acc[c2][nt] = mfma32(wfr[c2], ofr[nt], acc[c2][nt]);  // D[c, n]
  }
  float g = gamma[0];
  #pragma unroll
  for (int c2 = 0; c2 < 2; ++c2)
    #pragma unroll
    for (int nt = 0; nt < 2; ++nt)
      #pragma unroll
      for (int r = 0; r < 16; ++r) {
        int c = w * 64 + c2 * 32 + (r & 3) + 8 * (r >> 2) + 4 * hi;
        int n = n0 + nt * 32 + l31;
        size_t idx = (size_t)b * 256 * NPIX + (size_t)c * NPIX + n;
        out[idx] = g * (acc[c2][nt][r] + br[c]) + x[idx];
      }
}

extern "C" void kernel_launch(void* const* d_in, const int* in_sizes, int n_in,
                              void* d_out, int out_size, void* d_ws, size_t ws_size,
                              hipStream_t stream) {
  const float* x     = (const float*)d_in[0];
  const float* Wk    = (const float*)d_in[1];
  const float* bk    = (const float*)d_in[2];
  const float* Wq    = (const float*)d_in[3];
  const float* bq    = (const float*)d_in[4];
  const float* Wv    = (const float*)d_in[5];
  const float* bv    = (const float*)d_in[6];
  const float* Wr    = (const float*)d_in[7];
  const float* br    = (const float*)d_in[8];
  const float* gamma = (const float*)d_in[9];

  const size_t OFF_QT  = 0;
  const size_t OFF_KT  = 8388608;
  const size_t OFF_V   = 16777216;
  const size_t OFF_OT  = 33554432;
  const size_t OFF_WQK = 50331648;
  const size_t OFF_WV  = 50462720;
  const size_t OFF_WR  = 50593792;
  const size_t NEED    = 50724864;
  if (ws_size < NEED) return;  // cannot run without scratch

  char* ws = (char*)d_ws;
  unsigned short* qT  = (unsigned short*)(ws + OFF_QT);
  unsigned short* kT  = (unsigned short*)(ws + OFF_KT);
  unsigned short* vV  = (unsigned short*)(ws + OFF_V);
  unsigned short* oT  = (unsigned short*)(ws + OFF_OT);
  unsigned short* wqk = (unsigned short*)(ws + OFF_WQK);
  unsigned short* wvb = (unsigned short*)(ws + OFF_WV);
  unsigned short* wrb = (unsigned short*)(ws + OFF_WR);

  k_cvt<<<256, 256, 0, stream>>>(Wq, Wk, Wv, Wr, wqk, wvb, wrb);
  k_qkv<<<512, 256, 0, stream>>>(x, wqk, wvb, bq, bk, bv, qT, kT, vV);
  k_attn<<<256, 256, 0, stream>>>(qT, kT, vV, oT);
  k_out<<<512, 256, 0, stream>>>(oT, wrb, br, gamma, x, (float*)d_out);
}

// Round 8
// 258.160 us; speedup vs baseline: 1.5790x; 1.0238x over previous
//
#include <hip/hip_runtime.h>
#include <hip/hip_bf16.h>
#include <stdint.h>

#define NPIX 4096

typedef __attribute__((ext_vector_type(8))) short bf16x8;
typedef __attribute__((ext_vector_type(16))) float f32x16;
typedef __attribute__((ext_vector_type(4))) unsigned int uint4v;

__device__ __forceinline__ unsigned short bfb(float f) {
  __hip_bfloat16 h = __float2bfloat16(f);
  return __builtin_bit_cast(unsigned short, h);
}
__device__ __forceinline__ unsigned pack2(float a, float b) {
  return (unsigned)bfb(a) | ((unsigned)bfb(b) << 16);
}
__device__ __forceinline__ float bs(short v) {  // bf16 bits -> f32
  return __builtin_bit_cast(float, (unsigned)(unsigned short)v << 16);
}
__device__ __forceinline__ f32x16 mfma32(bf16x8 a, bf16x8 b, f32x16 c) {
  return __builtin_amdgcn_mfma_f32_32x32x16_bf16(a, b, c, 0, 0, 0);
}

// ---------------- kernel 0: convert weights to bf16 ----------------
__global__ void k_cvt(const float* __restrict__ Wq, const float* __restrict__ Wk,
                      const float* __restrict__ Wv, const float* __restrict__ Wr,
                      unsigned short* __restrict__ wqk, unsigned short* __restrict__ wv,
                      unsigned short* __restrict__ wr) {
  int i = blockIdx.x * 256 + threadIdx.x;  // 0..65535
  wqk[i] = bfb(i < 32768 ? Wq[i] : Wk[i - 32768]);
  wv[i]  = bfb(Wv[i]);
  wr[i]  = bfb(Wr[i]);
}

// ---------------- kernel 1: qkv projections ----------------
// out: qT [B][N][128] bf16, kT [B][N][128] bf16, v [B][256][N] bf16
__launch_bounds__(256, 2)
__global__ void k_qkv(const float* __restrict__ x,
                      const unsigned short* __restrict__ wqk,
                      const unsigned short* __restrict__ wv,
                      const float* __restrict__ bq, const float* __restrict__ bk,
                      const float* __restrict__ bv,
                      unsigned short* __restrict__ qT, unsigned short* __restrict__ kT,
                      unsigned short* __restrict__ vV) {
  __shared__ __align__(16) unsigned short xT[64 * 256];  // [n][c] bf16, swizzled rows of 512B
  const int b = blockIdx.x & 7;
  const int n0 = (blockIdx.x >> 3) * 64;
  const int t = threadIdx.x;
  const float* xb = x + (size_t)b * 256 * NPIX;
  #pragma unroll
  for (int p = 0; p < 16; ++p) {
    int c = (t >> 4) + p * 16;
    int nq = (t & 15) * 4;
    float4 f = *reinterpret_cast<const float4*>(xb + (size_t)c * NPIX + n0 + nq);
    float vals[4] = {f.x, f.y, f.z, f.w};
    #pragma unroll
    for (int j = 0; j < 4; ++j) {
      int n = nq + j;
      int byteoff = n * 512 + ((c * 2) ^ ((n & 7) << 4));
      xT[byteoff >> 1] = bfb(vals[j]);
    }
  }
  __syncthreads();
  const int lane = t & 63, w = t >> 6, l31 = lane & 31, hi = lane >> 5;
  f32x16 aq[2][2], av[2][2];
  #pragma unroll
  for (int a0 = 0; a0 < 2; ++a0)
    #pragma unroll
    for (int a1 = 0; a1 < 2; ++a1)
      #pragma unroll
      for (int i = 0; i < 16; ++i) { aq[a0][a1][i] = 0.f; av[a0][a1][i] = 0.f; }
  #pragma unroll
  for (int s = 0; s < 16; ++s) {  // K = 256 = 16 steps of 16
    bf16x8 xa[2];
    #pragma unroll
    for (int nt = 0; nt < 2; ++nt) {
      int n = nt * 32 + l31;
      int byteoff = n * 512 + (((s * 32 + hi * 16)) ^ ((n & 7) << 4));
      xa[nt] = *reinterpret_cast<const bf16x8*>(reinterpret_cast<const char*>(xT) + byteoff);
    }
    #pragma unroll
    for (int oc2 = 0; oc2 < 2; ++oc2) {
      int oc = w * 64 + oc2 * 32 + l31;
      bf16x8 wq = *reinterpret_cast<const bf16x8*>(wqk + oc * 256 + s * 16 + hi * 8);
      bf16x8 wvf = *reinterpret_cast<const bf16x8*>(wv + oc * 256 + s * 16 + hi * 8);
      #pragma unroll
      for (int nt = 0; nt < 2; ++nt) {
        aq[oc2][nt] = mfma32(xa[nt], wq, aq[oc2][nt]);   // D[n, oc]
        av[oc2][nt] = mfma32(wvf, xa[nt], av[oc2][nt]);  // D[vc, n]
      }
    }
  }
  #pragma unroll
  for (int oc2 = 0; oc2 < 2; ++oc2) {
    int oc = w * 64 + oc2 * 32 + l31;
    float bias = (oc < 128) ? bq[oc] : bk[oc - 128];
    unsigned short* dst = (oc < 128) ? (qT + (size_t)b * NPIX * 128 + oc)
                                     : (kT + (size_t)b * NPIX * 128 + (oc - 128));
    #pragma unroll
    for (int nt = 0; nt < 2; ++nt)
      #pragma unroll
      for (int r = 0; r < 16; ++r) {
        int n = n0 + nt * 32 + (r & 3) + 8 * (r >> 2) + 4 * hi;
        dst[(size_t)n * 128] = bfb(aq[oc2][nt][r] + bias);
      }
  }
  unsigned short* vb = vV + (size_t)b * 256 * NPIX;
  #pragma unroll
  for (int vc2 = 0; vc2 < 2; ++vc2)
    #pragma unroll
    for (int nt = 0; nt < 2; ++nt)
      #pragma unroll
      for (int r = 0; r < 16; ++r) {
        int vc = w * 64 + vc2 * 32 + (r & 3) + 8 * (r >> 2) + 4 * hi;
        int n = n0 + nt * 32 + l31;
        vb[(size_t)vc * NPIX + n] = bfb(av[vc2][nt][r] + bv[vc]);
      }
}

// ---------------- kernel 2: fused flash attention, inter-block split-K ----------------
// R1-proven structure: 4 waves x 32q x 256vc, QBLK=128, KVBLK=64, single-buffer
// stage->sync->compute->sync. split=1: grid 512, each block does 32 key-tiles
// (h = key-half), writes normalized O-hat (bf16) + lse. split=0: grid 256, 64 tiles.
// Zero-conflict swizzles (R7-verified): K ^((row&15)<<4); V packed 2vc/256B row.
__launch_bounds__(256, 2)
__global__ void k_attn(const unsigned short* __restrict__ qT,
                       const unsigned short* __restrict__ kT,
                       const unsigned short* __restrict__ vV,
                       unsigned short* __restrict__ o0,
                       unsigned short* __restrict__ o1,
                       float* __restrict__ lse, int split) {
  __shared__ __align__(16) char smem[49152];  // K 16KB + V 32KB
  const int b = blockIdx.x & 7;          // XCD-affine: one batch per XCD
  const int rest = blockIdx.x >> 3;
  const int qt = rest >> split;
  const int h = rest & split;
  const int nkt = 64 >> split;
  const int kt0 = h * nkt;
  const int t = threadIdx.x, lane = t & 63, l31 = lane & 31, hi = lane >> 5;
  const int sw = t >> 6;
  const int qp = qt * 128 + sw * 32 + l31;
  const unsigned short* qTb = qT + (size_t)b * NPIX * 128;
  const char* kTb = (const char*)(kT + (size_t)b * NPIX * 128);
  const char* vb  = (const char*)(vV + (size_t)b * 256 * NPIX);

  // staging geometry (constant across tiles)
  int kGl[4], kLds[4];
  #pragma unroll
  for (int i = 0; i < 4; ++i) {
    int row = sw * 16 + i * 4 + (lane >> 4);
    int c2 = (lane & 15) * 16;
    kGl[i]  = row * 256 + c2;
    kLds[i] = row * 256 + (c2 ^ ((row & 15) << 4));
  }
  int vGl[8], vLds[8];
  #pragma unroll
  for (int i = 0; i < 8; ++i) {
    int vc = sw * 64 + i * 8 + (lane >> 3);
    int c2 = (lane & 7) * 16;
    vGl[i]  = vc * 8192 + c2;
    vLds[i] = (vc >> 1) * 256 + (((vc & 1) * 128 + c2) ^ (((vc >> 1) & 15) << 4));
  }
  int kRowBase[2], kRowSwz[2];
  #pragma unroll
  for (int rt = 0; rt < 2; ++rt) {
    int row = rt * 32 + l31;
    kRowBase[rt] = row * 256;
    kRowSwz[rt]  = (row & 15) << 4;
  }
  int vBase[8], vSwz[8];
  #pragma unroll
  for (int vt = 0; vt < 8; ++vt) {
    int vc = vt * 32 + l31;
    vBase[vt] = (vc >> 1) * 256;
    vSwz[vt]  = ((vc >> 1) & 15) << 4;
  }
  const int vHalf = (l31 & 1) * 128;

  bf16x8 qf[8];
  #pragma unroll
  for (int s = 0; s < 8; ++s)
    qf[s] = *reinterpret_cast<const bf16x8*>(qTb + (size_t)qp * 128 + s * 16 + hi * 8);
  f32x16 O[8];
  #pragma unroll
  for (int vt = 0; vt < 8; ++vt)
    #pragma unroll
    for (int i = 0; i < 16; ++i) O[vt][i] = 0.f;
  float m_run = -3.0e38f, l_run = 0.0f;

  for (int kt = kt0; kt < kt0 + nkt; ++kt) {
    // stage K tile [64][128] + V tile [256][64] (zero-conflict swizzled)
    const char* kg = kTb + (size_t)kt * 16384;
    const char* vg = vb + (size_t)kt * 128;
    char* Kl = smem;
    char* Vl = smem + 16384;
    #pragma unroll
    for (int i = 0; i < 4; ++i) {
      uint4v d = *reinterpret_cast<const uint4v*>(kg + kGl[i]);
      *reinterpret_cast<uint4v*>(Kl + kLds[i]) = d;
    }
    #pragma unroll
    for (int i = 0; i < 8; ++i) {
      uint4v d = *reinterpret_cast<const uint4v*>(vg + vGl[i]);
      *reinterpret_cast<uint4v*>(Vl + vLds[i]) = d;
    }
    __syncthreads();
    #pragma unroll
    for (int rt = 0; rt < 2; ++rt) {
      f32x16 S;
      #pragma unroll
      for (int i = 0; i < 16; ++i) S[i] = 0.f;
      __builtin_amdgcn_s_setprio(1);
      #pragma unroll
      for (int s = 0; s < 8; ++s) {  // d = 128 = 8 steps
        bf16x8 ka = *reinterpret_cast<const bf16x8*>(
            Kl + kRowBase[rt] + ((s * 32 + hi * 16) ^ kRowSwz[rt]));
        S = mfma32(ka, qf[s], S);  // S^T[kp][qp]
      }
      __builtin_amdgcn_s_setprio(0);
      // key-wise max: in-lane 16 + partner lane^32
      float mx = fmaxf(fmaxf(fmaxf(S[0], S[1]), fmaxf(S[2], S[3])),
                       fmaxf(fmaxf(S[4], S[5]), fmaxf(S[6], S[7])));
      mx = fmaxf(mx, fmaxf(fmaxf(fmaxf(S[8], S[9]), fmaxf(S[10], S[11])),
                           fmaxf(fmaxf(S[12], S[13]), fmaxf(S[14], S[15]))));
      mx = fmaxf(mx, __shfl_xor(mx, 32));
      if (__any(mx > m_run + 8.0f)) {  // defer-max (T13)
        float mn = fmaxf(m_run, mx);
        float al = __expf(m_run - mn);
        l_run *= al;
        #pragma unroll
        for (int vt = 0; vt < 8; ++vt)
          #pragma unroll
          for (int i = 0; i < 16; ++i) O[vt][i] *= al;
        m_run = mn;
      }
      float sum = 0.f;
      #pragma unroll
      for (int i = 0; i < 16; ++i) { S[i] = __expf(S[i] - m_run); sum += S[i]; }
      sum += __shfl_xor(sum, 32);
      l_run += sum;
      // pack P to bf16 fragments: pairs + half swaps
      unsigned wd[8];
      #pragma unroll
      for (int i = 0; i < 8; ++i) wd[i] = pack2(S[2 * i], S[2 * i + 1]);
      #pragma unroll
      for (int pr = 0; pr < 4; ++pr) {
        int ia = (pr & 1) + (pr >> 1) * 4;      // 0,1,4,5
        int ib = ia + 2;                         // 2,3,6,7
        unsigned xs = (unsigned)__shfl_xor((int)wd[ia], 32);
        unsigned ys = (unsigned)__shfl_xor((int)wd[ib], 32);
        unsigned na = hi ? ys : wd[ia];
        unsigned nb = hi ? wd[ib] : xs;
        wd[ia] = na; wd[ib] = nb;
      }
      bf16x8 pf[2];
      { uint4v u; u.x = wd[0]; u.y = wd[1]; u.z = wd[2]; u.w = wd[3];
        pf[0] = __builtin_bit_cast(bf16x8, u); }
      { uint4v u; u.x = wd[4]; u.y = wd[5]; u.z = wd[6]; u.w = wd[7];
        pf[1] = __builtin_bit_cast(bf16x8, u); }
      // PV: O^T[vc][qp] += V[vc,kp] * P^T[kp,qp]
      __builtin_amdgcn_s_setprio(1);
      #pragma unroll
      for (int sl = 0; sl < 2; ++sl) {
        int ks = rt * 2 + sl;
        #pragma unroll
        for (int vt = 0; vt < 8; ++vt) {
          bf16x8 va = *reinterpret_cast<const bf16x8*>(
              Vl + vBase[vt] + ((vHalf + ks * 32 + hi * 16) ^ vSwz[vt]));
          O[vt] = mfma32(va, pf[sl], O[vt]);
        }
      }
      __builtin_amdgcn_s_setprio(0);
    }
    __syncthreads();
  }
  // epilogue: normalized O-hat (bf16) + lse
  float rl = 1.0f / l_run;
  unsigned short* oPtr = (h ? o1 : o0) + (size_t)b * NPIX * 256;  // [qp][vc]
  #pragma unroll
  for (int vt = 0; vt < 8; ++vt)
    #pragma unroll
    for (int i = 0; i < 16; i += 2) {
      int vc = vt * 32 + (i & 3) + 8 * (i >> 2) + 4 * hi;
      unsigned pk = pack2(O[vt][i] * rl, O[vt][i + 1] * rl);
      *reinterpret_cast<unsigned*>(oPtr + (size_t)qp * 256 + vc) = pk;
    }
  lse[h * 32768 + b * 4096 + qp] = m_run + __logf(l_run);
}

// ---------------- kernel 3: merge halves + output projection + residual ----------------
__launch_bounds__(256, 2)
__global__ void k_out(const unsigned short* __restrict__ o0,
                      const unsigned short* __restrict__ o1,
                      const float* __restrict__ lse0, const float* __restrict__ lse1,
                      const unsigned short* __restrict__ wr,
                      const float* __restrict__ br, const float* __restrict__ gamma,
                      const float* __restrict__ x, float* __restrict__ out) {
  const int b = blockIdx.x & 7;
  const int n0 = (blockIdx.x >> 3) * 64;
  const int t = threadIdx.x, w = t >> 6, lane = t & 63, l31 = lane & 31, hi = lane >> 5;
  const unsigned short* o0b = o0 + (size_t)b * NPIX * 256;
  const unsigned short* o1b = o1 + (size_t)b * NPIX * 256;
  // per-row merge weights (exact flash combine; degenerates to 0.5/0.5 when
  // o1==o0 && lse1==lse0 in non-split mode)
  float w0f[2], w1f[2];
  int nrow[2];
  #pragma unroll
  for (int nt = 0; nt < 2; ++nt) {
    int n = n0 + nt * 32 + l31;
    nrow[nt] = n;
    float f0 = lse0[b * 4096 + n], f1 = lse1[b * 4096 + n];
    float M = fmaxf(f0, f1);
    float e0 = __expf(f0 - M), e1 = __expf(f1 - M);
    float inv = 1.0f / (e0 + e1);
    w0f[nt] = e0 * inv;
    w1f[nt] = e1 * inv;
  }
  f32x16 acc[2][2];
  #pragma unroll
  for (int a0 = 0; a0 < 2; ++a0)
    #pragma unroll
    for (int a1 = 0; a1 < 2; ++a1)
      #pragma unroll
      for (int i = 0; i < 16; ++i) acc[a0][a1][i] = 0.f;
  #pragma unroll
  for (int s = 0; s < 16; ++s) {  // K = 256 (vc)
    bf16x8 ofr[2], wfr[2];
    #pragma unroll
    for (int nt = 0; nt < 2; ++nt) {
      size_t off = (size_t)nrow[nt] * 256 + s * 16 + hi * 8;
      bf16x8 a0 = *reinterpret_cast<const bf16x8*>(o0b + off);
      bf16x8 a1 = *reinterpret_cast<const bf16x8*>(o1b + off);
      unsigned u[4];
      #pragma unroll
      for (int p = 0; p < 4; ++p) {
        float m0 = w0f[nt] * bs(a0[2 * p])     + w1f[nt] * bs(a1[2 * p]);
        float m1 = w0f[nt] * bs(a0[2 * p + 1]) + w1f[nt] * bs(a1[2 * p + 1]);
        u[p] = pack2(m0, m1);
      }
      uint4v uv; uv.x = u[0]; uv.y = u[1]; uv.z = u[2]; uv.w = u[3];
      ofr[nt] = __builtin_bit_cast(bf16x8, uv);
    }
    #pragma unroll
    for (int c2 = 0; c2 < 2; ++c2) {
      int c = w * 64 + c2 * 32 + l31;
      wfr[c2] = *reinterpret_cast<const bf16x8*>(wr + c * 256 + s * 16 + hi * 8);
    }
    #pragma unroll
    for (int c2 = 0; c2 < 2; ++c2)
      #pragma unroll
      for (int nt = 0; nt < 2; ++nt)
        acc[c2][nt] = mfma32(wfr[c2], ofr[nt], acc[c2][nt]);  // D[c, n]
  }
  float g = gamma[0];
  #pragma unroll
  for (int c2 = 0; c2 < 2; ++c2)
    #pragma unroll
    for (int nt = 0; nt < 2; ++nt)
      #pragma unroll
      for (int r = 0; r < 16; ++r) {
        int c = w * 64 + c2 * 32 + (r & 3) + 8 * (r >> 2) + 4 * hi;
        int n = n0 + nt * 32 + l31;
        size_t idx = (size_t)b * 256 * NPIX + (size_t)c * NPIX + n;
        out[idx] = g * (acc[c2][nt][r] + br[c]) + x[idx];
      }
}

extern "C" void kernel_launch(void* const* d_in, const int* in_sizes, int n_in,
                              void* d_out, int out_size, void* d_ws, size_t ws_size,
                              hipStream_t stream) {
  const float* x     = (const float*)d_in[0];
  const float* Wk    = (const float*)d_in[1];
  const float* bk    = (const float*)d_in[2];
  const float* Wq    = (const float*)d_in[3];
  const float* bq    = (const float*)d_in[4];
  const float* Wv    = (const float*)d_in[5];
  const float* bv    = (const float*)d_in[6];
  const float* Wr    = (const float*)d_in[7];
  const float* br    = (const float*)d_in[8];
  const float* gamma = (const float*)d_in[9];

  // Shared: qT 8M | kT 8M | vV 16M | o0 16M
  // split : + o1 16M, weights at 64M, lse overlaps wqk+wv (written after k_qkv)
  // base  : weights at 48M, lse overlaps wqk+wv. NEED_BASE == proven 50724864.
  const size_t OFF_QT = 0;
  const size_t OFF_KT = 8388608;
  const size_t OFF_V  = 16777216;
  const size_t OFF_O0 = 33554432;
  const size_t OFF_O1 = 50331648;
  const size_t NEED_SPLIT = 67502080;  // 64M + 384K weights
  const size_t NEED_BASE  = 50724864;
  if (ws_size < NEED_BASE) return;  // cannot run without scratch
  const int split = (ws_size >= NEED_SPLIT) ? 1 : 0;
  const size_t OFF_WQK = split ? 67108864 : 50331648;
  const size_t OFF_WV  = OFF_WQK + 131072;
  const size_t OFF_WR  = OFF_WQK + 262144;
  const size_t OFF_LSE = OFF_WQK;  // overlaps wqk+wv: dead after k_qkv

  char* ws = (char*)d_ws;
  unsigned short* qT  = (unsigned short*)(ws + OFF_QT);
  unsigned short* kT  = (unsigned short*)(ws + OFF_KT);
  unsigned short* vV  = (unsigned short*)(ws + OFF_V);
  unsigned short* o0  = (unsigned short*)(ws + OFF_O0);
  unsigned short* o1  = split ? (unsigned short*)(ws + OFF_O1) : o0;
  unsigned short* wqk = (unsigned short*)(ws + OFF_WQK);
  unsigned short* wvb = (unsigned short*)(ws + OFF_WV);
  unsigned short* wrb = (unsigned short*)(ws + OFF_WR);
  float* lse = (float*)(ws + OFF_LSE);
  float* lse1 = lse + (split ? 32768 : 0);

  k_cvt<<<256, 256, 0, stream>>>(Wq, Wk, Wv, Wr, wqk, wvb, wrb);
  k_qkv<<<512, 256, 0, stream>>>(x, wqk, wvb, bq, bk, bv, qT, kT, vV);
  k_attn<<<split ? 512 : 256, 256, 0, stream>>>(qT, kT, vV, o0, o1, lse, split);
  k_out<<<512, 256, 0, stream>>>(o0, o1, lse, lse1, wrb, br, gamma, x, (float*)d_out);
}

// Round 9
// 237.417 us; speedup vs baseline: 1.7169x; 1.0874x over previous
//
#include <hip/hip_runtime.h>
#include <hip/hip_bf16.h>
#include <stdint.h>

#define NPIX 4096

typedef __attribute__((ext_vector_type(8))) short bf16x8;
typedef __attribute__((ext_vector_type(16))) float f32x16;
typedef __attribute__((ext_vector_type(4))) unsigned int uint4v;
typedef __attribute__((address_space(1))) unsigned int gu32;
typedef __attribute__((address_space(3))) unsigned int lu32;

__device__ __forceinline__ unsigned short bfb(float f) {
  __hip_bfloat16 h = __float2bfloat16(f);
  return __builtin_bit_cast(unsigned short, h);
}
__device__ __forceinline__ unsigned pack2(float a, float b) {
  return (unsigned)bfb(a) | ((unsigned)bfb(b) << 16);
}
__device__ __forceinline__ f32x16 mfma32(bf16x8 a, bf16x8 b, f32x16 c) {
  return __builtin_amdgcn_mfma_f32_32x32x16_bf16(a, b, c, 0, 0, 0);
}

// ---------------- kernel 0: convert weights to bf16 ----------------
__global__ void k_cvt(const float* __restrict__ Wq, const float* __restrict__ Wk,
                      const float* __restrict__ Wv, const float* __restrict__ Wr,
                      unsigned short* __restrict__ wqk, unsigned short* __restrict__ wv,
                      unsigned short* __restrict__ wr) {
  int i = blockIdx.x * 256 + threadIdx.x;  // 0..65535
  wqk[i] = bfb(i < 32768 ? Wq[i] : Wk[i - 32768]);
  wv[i]  = bfb(Wv[i]);
  wr[i]  = bfb(Wr[i]);
}

// ---------------- kernel 1: qkv projections ----------------
// out: qT [B][N][128] bf16, kT [B][N][128] bf16, v [B][256][N] bf16
__launch_bounds__(256, 2)
__global__ void k_qkv(const float* __restrict__ x,
                      const unsigned short* __restrict__ wqk,
                      const unsigned short* __restrict__ wv,
                      const float* __restrict__ bq, const float* __restrict__ bk,
                      const float* __restrict__ bv,
                      unsigned short* __restrict__ qT, unsigned short* __restrict__ kT,
                      unsigned short* __restrict__ vV) {
  __shared__ __align__(16) unsigned short xT[64 * 256];  // [n][c] bf16, swizzled rows of 512B
  const int b = blockIdx.x & 7;
  const int n0 = (blockIdx.x >> 3) * 64;
  const int t = threadIdx.x;
  const float* xb = x + (size_t)b * 256 * NPIX;
  #pragma unroll
  for (int p = 0; p < 16; ++p) {
    int c = (t >> 4) + p * 16;
    int nq = (t & 15) * 4;
    float4 f = *reinterpret_cast<const float4*>(xb + (size_t)c * NPIX + n0 + nq);
    float vals[4] = {f.x, f.y, f.z, f.w};
    #pragma unroll
    for (int j = 0; j < 4; ++j) {
      int n = nq + j;
      int byteoff = n * 512 + ((c * 2) ^ ((n & 7) << 4));
      xT[byteoff >> 1] = bfb(vals[j]);
    }
  }
  __syncthreads();
  const int lane = t & 63, w = t >> 6, l31 = lane & 31, hi = lane >> 5;
  f32x16 aq[2][2], av[2][2];
  #pragma unroll
  for (int a0 = 0; a0 < 2; ++a0)
    #pragma unroll
    for (int a1 = 0; a1 < 2; ++a1)
      #pragma unroll
      for (int i = 0; i < 16; ++i) { aq[a0][a1][i] = 0.f; av[a0][a1][i] = 0.f; }
  #pragma unroll
  for (int s = 0; s < 16; ++s) {  // K = 256 = 16 steps of 16
    bf16x8 xa[2];
    #pragma unroll
    for (int nt = 0; nt < 2; ++nt) {
      int n = nt * 32 + l31;
      int byteoff = n * 512 + (((s * 32 + hi * 16)) ^ ((n & 7) << 4));
      xa[nt] = *reinterpret_cast<const bf16x8*>(reinterpret_cast<const char*>(xT) + byteoff);
    }
    #pragma unroll
    for (int oc2 = 0; oc2 < 2; ++oc2) {
      int oc = w * 64 + oc2 * 32 + l31;
      bf16x8 wq = *reinterpret_cast<const bf16x8*>(wqk + oc * 256 + s * 16 + hi * 8);
      bf16x8 wvf = *reinterpret_cast<const bf16x8*>(wv + oc * 256 + s * 16 + hi * 8);
      #pragma unroll
      for (int nt = 0; nt < 2; ++nt) {
        aq[oc2][nt] = mfma32(xa[nt], wq, aq[oc2][nt]);   // D[n, oc]
        av[oc2][nt] = mfma32(wvf, xa[nt], av[oc2][nt]);  // D[vc, n]
      }
    }
  }
  #pragma unroll
  for (int oc2 = 0; oc2 < 2; ++oc2) {
    int oc = w * 64 + oc2 * 32 + l31;
    float bias = (oc < 128) ? bq[oc] : bk[oc - 128];
    unsigned short* dst = (oc < 128) ? (qT + (size_t)b * NPIX * 128 + oc)
                                     : (kT + (size_t)b * NPIX * 128 + (oc - 128));
    #pragma unroll
    for (int nt = 0; nt < 2; ++nt)
      #pragma unroll
      for (int r = 0; r < 16; ++r) {
        int n = n0 + nt * 32 + (r & 3) + 8 * (r >> 2) + 4 * hi;
        dst[(size_t)n * 128] = bfb(aq[oc2][nt][r] + bias);
      }
  }
  unsigned short* vb = vV + (size_t)b * 256 * NPIX;
  #pragma unroll
  for (int vc2 = 0; vc2 < 2; ++vc2)
    #pragma unroll
    for (int nt = 0; nt < 2; ++nt)
      #pragma unroll
      for (int r = 0; r < 16; ++r) {
        int vc = w * 64 + vc2 * 32 + (r & 3) + 8 * (r >> 2) + 4 * hi;
        int n = n0 + nt * 32 + l31;
        vb[(size_t)vc * NPIX + n] = bfb(av[vc2][nt][r] + bv[vc]);
      }
}

// ---------------- kernel 2: fused flash attention ----------------
// R1 structure (4 waves x 32q x 256vc, QBLK=128, KVBLK=64, 1 fat wave/SIMD)
// + T3 2-phase pipeline via global_load_lds (direct HBM->LDS, prefetch next
// tile under compute, ONE barrier per tile) + m173 pre-swizzled global source
// (linear LDS dest). Zero-conflict layouts (R7-verified): K rows 256B
// ^((row&15)<<4); V packed 2 vc per 256B row ^(((vc>>1)&15)<<4).
__launch_bounds__(256, 1)
__global__ void k_attn(const unsigned short* __restrict__ qT,
                       const unsigned short* __restrict__ kT,
                       const unsigned short* __restrict__ vV,
                       unsigned short* __restrict__ oT) {
  __shared__ __align__(16) char smem[98304];  // 2 x (K 16KB + V 32KB)
  const int b = blockIdx.x & 7;          // XCD-affine: one batch per XCD
  const int qt = blockIdx.x >> 3;
  const int t = threadIdx.x, lane = t & 63, l31 = lane & 31, hi = lane >> 5;
  const int sw = t >> 6;
  const int qp = qt * 128 + sw * 32 + l31;
  const unsigned short* qTb = qT + (size_t)b * NPIX * 128;
  const char* kTb = (const char*)(kT + (size_t)b * NPIX * 128);
  const char* vb  = (const char*)(vV + (size_t)b * 256 * NPIX);

  // ---- staging geometry: lane-linear LDS dest (chunk*1024 + lane*16),
  //      inverse-swizzled global source (within-tile byte offsets) ----
  int kSrc[4], kDst[4];
  #pragma unroll
  for (int i = 0; i < 4; ++i) {
    int c = sw * 4 + i;                 // 16 chunks cover K rows 0..63
    int row = c * 4 + (lane >> 4);
    int c2 = (lane & 15) * 16;
    kSrc[i] = row * 256 + (c2 ^ ((row & 15) << 4));
    kDst[i] = c * 1024;
  }
  int vSrc[8], vDst[8];
  #pragma unroll
  for (int i = 0; i < 8; ++i) {
    int c = sw * 8 + i;                 // 32 chunks cover packed rows 0..127
    int pr = c * 4 + (lane >> 4);
    int z = ((lane & 15) * 16) ^ ((pr & 15) << 4);
    int vc = pr * 2 + (z >> 7);
    vSrc[i] = vc * 8192 + (z & 127);    // + kt*128 at issue
    vDst[i] = 16384 + c * 1024;
  }
  // ---- compute-phase read geometry ----
  int kRowBase[2], kRowSwz[2];
  #pragma unroll
  for (int rt = 0; rt < 2; ++rt) {
    int row = rt * 32 + l31;
    kRowBase[rt] = row * 256;
    kRowSwz[rt]  = (row & 15) << 4;
  }
  int vBase[8], vSwz[8];
  #pragma unroll
  for (int vt = 0; vt < 8; ++vt) {
    int vc = vt * 32 + l31;
    vBase[vt] = (vc >> 1) * 256;
    vSwz[vt]  = ((vc >> 1) & 15) << 4;
  }
  const int vHalf = (l31 & 1) * 128;

  bf16x8 qf[8];
  #pragma unroll
  for (int s = 0; s < 8; ++s)
    qf[s] = *reinterpret_cast<const bf16x8*>(qTb + (size_t)qp * 128 + s * 16 + hi * 8);
  f32x16 O[8];
  #pragma unroll
  for (int vt = 0; vt < 8; ++vt)
    #pragma unroll
    for (int i = 0; i < 16; ++i) O[vt][i] = 0.f;
  float m_run = -3.0e38f, l_run = 0.0f;

  // async stage of one whole K+V tile into buf (12 x global_load_lds width=16)
  auto STAGE = [&](char* buf, int kt) {
    const char* kg = kTb + (size_t)kt * 16384;
    const char* vg = vb + (size_t)kt * 128;
    #pragma unroll
    for (int i = 0; i < 4; ++i)
      __builtin_amdgcn_global_load_lds((gu32*)(kg + kSrc[i]),
                                       (lu32*)(buf + kDst[i]), 16, 0, 0);
    #pragma unroll
    for (int i = 0; i < 8; ++i)
      __builtin_amdgcn_global_load_lds((gu32*)(vg + vSrc[i]),
                                       (lu32*)(buf + vDst[i]), 16, 0, 0);
  };

  STAGE(smem, 0);
  __syncthreads();  // vmcnt(0) drained by barrier: tile 0 resident

  for (int kt = 0; kt < 64; ++kt) {
    char* Kl = smem + (kt & 1) * 49152;
    char* Vl = Kl + 16384;
    if (kt < 63) STAGE(smem + ((kt + 1) & 1) * 49152, kt + 1);  // fly under compute
    #pragma unroll
    for (int rt = 0; rt < 2; ++rt) {
      f32x16 S;
      #pragma unroll
      for (int i = 0; i < 16; ++i) S[i] = 0.f;
      __builtin_amdgcn_s_setprio(1);
      #pragma unroll
      for (int s = 0; s < 8; ++s) {  // d = 128 = 8 steps
        bf16x8 ka = *reinterpret_cast<const bf16x8*>(
            Kl + kRowBase[rt] + ((s * 32 + hi * 16) ^ kRowSwz[rt]));
        S = mfma32(ka, qf[s], S);  // S^T[kp][qp]
      }
      __builtin_amdgcn_s_setprio(0);
      // key-wise max: in-lane 16 + partner lane^32
      float mx = fmaxf(fmaxf(fmaxf(S[0], S[1]), fmaxf(S[2], S[3])),
                       fmaxf(fmaxf(S[4], S[5]), fmaxf(S[6], S[7])));
      mx = fmaxf(mx, fmaxf(fmaxf(fmaxf(S[8], S[9]), fmaxf(S[10], S[11])),
                           fmaxf(fmaxf(S[12], S[13]), fmaxf(S[14], S[15]))));
      mx = fmaxf(mx, __shfl_xor(mx, 32));
      if (__any(mx > m_run + 8.0f)) {  // defer-max (T13)
        float mn = fmaxf(m_run, mx);
        float al = __expf(m_run - mn);
        l_run *= al;
        #pragma unroll
        for (int vt = 0; vt < 8; ++vt)
          #pragma unroll
          for (int i = 0; i < 16; ++i) O[vt][i] *= al;
        m_run = mn;
      }
      float sum = 0.f;
      #pragma unroll
      for (int i = 0; i < 16; ++i) { S[i] = __expf(S[i] - m_run); sum += S[i]; }
      sum += __shfl_xor(sum, 32);
      l_run += sum;
      // pack P to bf16 fragments: pairs + half swaps
      unsigned wd[8];
      #pragma unroll
      for (int i = 0; i < 8; ++i) wd[i] = pack2(S[2 * i], S[2 * i + 1]);
      #pragma unroll
      for (int pr = 0; pr < 4; ++pr) {
        int ia = (pr & 1) + (pr >> 1) * 4;      // 0,1,4,5
        int ib = ia + 2;                         // 2,3,6,7
        unsigned xs = (unsigned)__shfl_xor((int)wd[ia], 32);
        unsigned ys = (unsigned)__shfl_xor((int)wd[ib], 32);
        unsigned na = hi ? ys : wd[ia];
        unsigned nb = hi ? wd[ib] : xs;
        wd[ia] = na; wd[ib] = nb;
      }
      bf16x8 pf[2];
      { uint4v u; u.x = wd[0]; u.y = wd[1]; u.z = wd[2]; u.w = wd[3];
        pf[0] = __builtin_bit_cast(bf16x8, u); }
      { uint4v u; u.x = wd[4]; u.y = wd[5]; u.z = wd[6]; u.w = wd[7];
        pf[1] = __builtin_bit_cast(bf16x8, u); }
      // PV: O^T[vc][qp] += V[vc,kp] * P^T[kp,qp]
      __builtin_amdgcn_s_setprio(1);
      #pragma unroll
      for (int sl = 0; sl < 2; ++sl) {
        int ks = rt * 2 + sl;
        #pragma unroll
        for (int vt = 0; vt < 8; ++vt) {
          bf16x8 va = *reinterpret_cast<const bf16x8*>(
              Vl + vBase[vt] + ((vHalf + ks * 32 + hi * 16) ^ vSwz[vt]));
          O[vt] = mfma32(va, pf[sl], O[vt]);
        }
      }
      __builtin_amdgcn_s_setprio(0);
    }
    // one barrier per tile: drains prefetch (vmcnt) + guards buffer reuse
    __syncthreads();
  }
  float rl = 1.0f / l_run;
  unsigned short* oTb = oT + (size_t)b * NPIX * 256;  // [qp][vc]
  #pragma unroll
  for (int vt = 0; vt < 8; ++vt)
    #pragma unroll
    for (int i = 0; i < 16; i += 2) {
      int vc = vt * 32 + (i & 3) + 8 * (i >> 2) + 4 * hi;
      unsigned pk = pack2(O[vt][i] * rl, O[vt][i + 1] * rl);
      *reinterpret_cast<unsigned*>(oTb + (size_t)qp * 256 + vc) = pk;
    }
}

// ---------------- kernel 3: output projection + residual ----------------
__launch_bounds__(256, 2)
__global__ void k_out(const unsigned short* __restrict__ oT,
                      const unsigned short* __restrict__ wr,
                      const float* __restrict__ br, const float* __restrict__ gamma,
                      const float* __restrict__ x, float* __restrict__ out) {
  const int b = blockIdx.x & 7;
  const int n0 = (blockIdx.x >> 3) * 64;
  const int t = threadIdx.x, w = t >> 6, lane = t & 63, l31 = lane & 31, hi = lane >> 5;
  const unsigned short* oTb = oT + (size_t)b * NPIX * 256;
  f32x16 acc[2][2];
  #pragma unroll
  for (int a0 = 0; a0 < 2; ++a0)
    #pragma unroll
    for (int a1 = 0; a1 < 2; ++a1)
      #pragma unroll
      for (int i = 0; i < 16; ++i) acc[a0][a1][i] = 0.f;
  #pragma unroll
  for (int s = 0; s < 16; ++s) {  // K = 256 (vc)
    bf16x8 ofr[2], wfr[2];
    #pragma unroll
    for (int nt = 0; nt < 2; ++nt) {
      int n = n0 + nt * 32 + l31;
      ofr[nt] = *reinterpret_cast<const bf16x8*>(oTb + (size_t)n * 256 + s * 16 + hi * 8);
    }
    #pragma unroll
    for (int c2 = 0; c2 < 2; ++c2) {
      int c = w * 64 + c2 * 32 + l31;
      wfr[c2] = *reinterpret_cast<const bf16x8*>(wr + c * 256 + s * 16 + hi * 8);
    }
    #pragma unroll
    for (int c2 = 0; c2 < 2; ++c2)
      #pragma unroll
      for (int nt = 0; nt < 2; ++nt)
        acc[c2][nt] = mfma32(wfr[c2], ofr[nt], acc[c2][nt]);  // D[c, n]
  }
  float g = gamma[0];
  #pragma unroll
  for (int c2 = 0; c2 < 2; ++c2)
    #pragma unroll
    for (int nt = 0; nt < 2; ++nt)
      #pragma unroll
      for (int r = 0; r < 16; ++r) {
        int c = w * 64 + c2 * 32 + (r & 3) + 8 * (r >> 2) + 4 * hi;
        int n = n0 + nt * 32 + l31;
        size_t idx = (size_t)b * 256 * NPIX + (size_t)c * NPIX + n;
        out[idx] = g * (acc[c2][nt][r] + br[c]) + x[idx];
      }
}

extern "C" void kernel_launch(void* const* d_in, const int* in_sizes, int n_in,
                              void* d_out, int out_size, void* d_ws, size_t ws_size,
                              hipStream_t stream) {
  const float* x     = (const float*)d_in[0];
  const float* Wk    = (const float*)d_in[1];
  const float* bk    = (const float*)d_in[2];
  const float* Wq    = (const float*)d_in[3];
  const float* bq    = (const float*)d_in[4];
  const float* Wv    = (const float*)d_in[5];
  const float* bv    = (const float*)d_in[6];
  const float* Wr    = (const float*)d_in[7];
  const float* br    = (const float*)d_in[8];
  const float* gamma = (const float*)d_in[9];

  const size_t OFF_QT  = 0;
  const size_t OFF_KT  = 8388608;
  const size_t OFF_V   = 16777216;
  const size_t OFF_OT  = 33554432;
  const size_t OFF_WQK = 50331648;
  const size_t OFF_WV  = 50462720;
  const size_t OFF_WR  = 50593792;
  const size_t NEED    = 50724864;
  if (ws_size < NEED) return;  // cannot run without scratch

  char* ws = (char*)d_ws;
  unsigned short* qT  = (unsigned short*)(ws + OFF_QT);
  unsigned short* kT  = (unsigned short*)(ws + OFF_KT);
  unsigned short* vV  = (unsigned short*)(ws + OFF_V);
  unsigned short* oT  = (unsigned short*)(ws + OFF_OT);
  unsigned short* wqk = (unsigned short*)(ws + OFF_WQK);
  unsigned short* wvb = (unsigned short*)(ws + OFF_WV);
  unsigned short* wrb = (unsigned short*)(ws + OFF_WR);

  k_cvt<<<256, 256, 0, stream>>>(Wq, Wk, Wv, Wr, wqk, wvb, wrb);
  k_qkv<<<512, 256, 0, stream>>>(x, wqk, wvb, bq, bk, bv, qT, kT, vV);
  k_attn<<<256, 256, 0, stream>>>(qT, kT, vV, oT);
  k_out<<<512, 256, 0, stream>>>(oT, wrb, br, gamma, x, (float*)d_out);
}